// Round 15
// baseline (263.317 us; speedup 1.0000x reference)
//
#include <hip/hip_runtime.h>

typedef __attribute__((ext_vector_type(8))) short bf16x8;
typedef __attribute__((ext_vector_type(4))) float f32x4;

#define DEVI static __device__ __forceinline__

constexpr float NEGV = -1e9f;

DEVI unsigned short f2b(float f) {
  union { float f; unsigned int u; } c; c.f = f;
  unsigned int lsb = (c.u >> 16) & 1u;
  return (unsigned short)((c.u + 0x7fffu + lsb) >> 16);
}
DEVI float sb2f(short s) {
  union { unsigned int u; float f; } c;
  c.u = ((unsigned int)(unsigned short)s) << 16;
  return c.f;
}

DEVI void gload16(const unsigned short* g, unsigned short* l) {
  __builtin_amdgcn_global_load_lds(
      (const __attribute__((address_space(1))) unsigned int*)g,
      (__attribute__((address_space(3))) unsigned int*)l, 16, 0, 0);
}

// ---------------- mask canonicalization -> bit-packed [B*1024][32 u32] -----
__global__ void mask_detect(const unsigned int* __restrict__ m, int n, int* flag) {
  unsigned int v = 0;
  for (int i = blockIdx.x * blockDim.x + threadIdx.x; i < n; i += gridDim.x * blockDim.x)
    v |= m[i];
  if (v & ~1u) atomicOr(flag, 1);
}

__global__ void mask_canon_bits(const void* __restrict__ mraw, unsigned int* __restrict__ mb,
                                int nwords, const int* __restrict__ flag) {
  int i = blockIdx.x * blockDim.x + threadIdx.x;
  if (i >= nwords) return;
  bool isbytes = (*flag != 0);
  unsigned int out = 0;
  if (isbytes) {
    const unsigned int* p = (const unsigned int*)mraw + (size_t)i * 8;
    #pragma unroll
    for (int w = 0; w < 8; w++) {
      unsigned int bw = p[w];
      out |= ((bw & 1u) << (w * 4)) | (((bw >> 8) & 1u) << (w * 4 + 1)) |
             (((bw >> 16) & 1u) << (w * 4 + 2)) | (((bw >> 24) & 1u) << (w * 4 + 3));
    }
  } else {
    const int4* p = (const int4*)mraw + (size_t)i * 8;
    #pragma unroll
    for (int w = 0; w < 8; w++) {
      int4 v = p[w];
      out |= ((v.x != 0 ? 1u : 0u) << (w * 4)) | ((v.y != 0 ? 1u : 0u) << (w * 4 + 1)) |
             ((v.z != 0 ? 1u : 0u) << (w * 4 + 2)) | ((v.w != 0 ? 1u : 0u) << (w * 4 + 3));
    }
  }
  mb[i] = out;
}

// ---------------- LayerNorm over D=512, one row per block, bf16 out --------
__global__ __launch_bounds__(256) void ln_kernel(const float* __restrict__ q,
    const float* __restrict__ gamma, const float* __restrict__ beta,
    unsigned short* __restrict__ qn) {
  int row = blockIdx.x;
  int t = threadIdx.x;
  const float* x = q + (size_t)row * 512;
  float2 v = reinterpret_cast<const float2*>(x)[t];
  float s = v.x + v.y, s2 = v.x * v.x + v.y * v.y;
  #pragma unroll
  for (int o = 32; o; o >>= 1) { s += __shfl_xor(s, o); s2 += __shfl_xor(s2, o); }
  __shared__ float ls[4], ls2[4];
  int w = t >> 6;
  if ((t & 63) == 0) { ls[w] = s; ls2[w] = s2; }
  __syncthreads();
  float S = ls[0] + ls[1] + ls[2] + ls[3];
  float S2 = ls2[0] + ls2[1] + ls2[2] + ls2[3];
  float mu = S * (1.f / 512.f);
  float var = S2 * (1.f / 512.f) - mu * mu;
  float r = rsqrtf(var + 1e-6f);
  float g0 = gamma[t * 2], g1 = gamma[t * 2 + 1];
  float b0 = beta[t * 2], b1 = beta[t * 2 + 1];
  ushort2 o;
  o.x = f2b((v.x - mu) * r * g0 + b0);
  o.y = f2b((v.y - mu) * r * g1 + b1);
  reinterpret_cast<ushort2*>(qn + (size_t)row * 512)[t] = o;
}

// ---------------- 128x128-tile projection GEMM, z-batched over 4 outputs ---
// grid (64, 4, 4): z = {qen, qex, khb, vhT}. Y = X @ W^T (K=512), bf16 MFMA.
__global__ __launch_bounds__(256) void proj_gemm(
    const unsigned short* __restrict__ qn, const float* __restrict__ kf,
    const float* __restrict__ vf,
    const float* __restrict__ w_qs, const float* __restrict__ w_ex,
    const float* __restrict__ w_ks, const float* __restrict__ w_vs,
    unsigned short* __restrict__ qen, unsigned short* __restrict__ qex,
    unsigned short* __restrict__ khb, unsigned short* __restrict__ vhT) {
  constexpr int LDT = 40;
  __shared__ __align__(16) unsigned short lA[128 * LDT];
  __shared__ __align__(16) unsigned short lB[128 * LDT];
  int z = blockIdx.z;
  const float* W = (z == 0) ? w_qs : (z == 1) ? w_ex : (z == 2) ? w_ks : w_vs;
  float scale = (z < 2) ? 0.125f : 1.0f;
  int t = threadIdx.x, w = t >> 6, l = t & 63, lr = l & 15, lg = l >> 4;
  int wr = w >> 1, wc = w & 1;
  int mt = blockIdx.x * 128, nt = blockIdx.y * 128;
  f32x4 acc[4][4];
  #pragma unroll
  for (int i = 0; i < 4; i++)
    #pragma unroll
    for (int jj = 0; jj < 4; jj++) acc[i][jj] = {0.f, 0.f, 0.f, 0.f};
  int sr = t >> 1, sc = (t & 1) * 16;
  for (int k0 = 0; k0 < 512; k0 += 32) {
    __syncthreads();
    if (z < 2) {
      const unsigned short* src = qn + (size_t)(mt + sr) * 512 + k0 + sc;
      *reinterpret_cast<float4*>(&lA[sr * LDT + sc]) =
          *reinterpret_cast<const float4*>(src);
      *reinterpret_cast<float4*>(&lA[sr * LDT + sc + 8]) =
          *reinterpret_cast<const float4*>(src + 8);
    } else {
      const float* src = ((z == 2) ? kf : vf) + (size_t)(mt + sr) * 512 + k0 + sc;
      #pragma unroll
      for (int i = 0; i < 4; i++) {
        float4 x = *reinterpret_cast<const float4*>(src + i * 4);
        ushort4 hh{f2b(x.x), f2b(x.y), f2b(x.z), f2b(x.w)};
        *reinterpret_cast<ushort4*>(&lA[sr * LDT + sc + i * 4]) = hh;
      }
    }
    {
      const float* src = W + (size_t)(nt + sr) * 512 + k0 + sc;
      #pragma unroll
      for (int i = 0; i < 4; i++) {
        float4 x = *reinterpret_cast<const float4*>(src + i * 4);
        ushort4 hh{f2b(x.x), f2b(x.y), f2b(x.z), f2b(x.w)};
        *reinterpret_cast<ushort4*>(&lB[sr * LDT + sc + i * 4]) = hh;
      }
    }
    __syncthreads();
    bf16x8 aF[4], bF[4];
    #pragma unroll
    for (int ai = 0; ai < 4; ai++)
      aF[ai] = *reinterpret_cast<const bf16x8*>(&lA[(wr * 64 + ai * 16 + lr) * LDT + lg * 8]);
    #pragma unroll
    for (int bj = 0; bj < 4; bj++)
      bF[bj] = *reinterpret_cast<const bf16x8*>(&lB[(wc * 64 + bj * 16 + lr) * LDT + lg * 8]);
    #pragma unroll
    for (int ai = 0; ai < 4; ai++)
      #pragma unroll
      for (int bj = 0; bj < 4; bj++)
        acc[ai][bj] = __builtin_amdgcn_mfma_f32_16x16x32_bf16(aF[ai], bF[bj], acc[ai][bj], 0, 0, 0);
  }
  unsigned short* Y = (z == 0) ? qen : (z == 1) ? qex : (z == 2) ? khb : vhT;
  #pragma unroll
  for (int ai = 0; ai < 4; ai++) {
    #pragma unroll
    for (int bj = 0; bj < 4; bj++) {
      #pragma unroll
      for (int j = 0; j < 4; j++) {
        int m = mt + wr * 64 + ai * 16 + lg * 4 + j;
        int c = nt + wc * 64 + bj * 16 + lr;
        unsigned short o = f2b(acc[ai][bj][j] * scale);
        if (z < 3) {
          Y[(size_t)m * 512 + c] = o;
        } else {
          int bb_ = m >> 10, ll = m & 1023, hh = c >> 6, dd = c & 63;
          Y[((size_t)((bb_ * 8 + hh) * 64 + dd)) * 1024 + ll] = o;
        }
      }
    }
  }
}

// ---------------- 128x128-tile FC GEMM: out = ao @ w_fc^T + bias + resid ---
__global__ __launch_bounds__(256) void fc_gemm(
    const unsigned short* __restrict__ ao, const float* __restrict__ w_fc,
    const float* __restrict__ bias, const float* __restrict__ resid,
    float* __restrict__ out) {
  constexpr int LDT = 40;
  __shared__ __align__(16) unsigned short lA[128 * LDT];
  __shared__ __align__(16) unsigned short lB[128 * LDT];
  int t = threadIdx.x, w = t >> 6, l = t & 63, lr = l & 15, lg = l >> 4;
  int wr = w >> 1, wc = w & 1;
  int mt = blockIdx.x * 128, nt = blockIdx.y * 128;
  f32x4 acc[4][4];
  #pragma unroll
  for (int i = 0; i < 4; i++)
    #pragma unroll
    for (int jj = 0; jj < 4; jj++) acc[i][jj] = {0.f, 0.f, 0.f, 0.f};
  int sr = t >> 1, sc = (t & 1) * 16;
  for (int k0 = 0; k0 < 512; k0 += 32) {
    __syncthreads();
    {
      const unsigned short* src = ao + (size_t)(mt + sr) * 512 + k0 + sc;
      *reinterpret_cast<float4*>(&lA[sr * LDT + sc]) =
          *reinterpret_cast<const float4*>(src);
      *reinterpret_cast<float4*>(&lA[sr * LDT + sc + 8]) =
          *reinterpret_cast<const float4*>(src + 8);
    }
    {
      const float* src = w_fc + (size_t)(nt + sr) * 512 + k0 + sc;
      #pragma unroll
      for (int i = 0; i < 4; i++) {
        float4 x = *reinterpret_cast<const float4*>(src + i * 4);
        ushort4 hh{f2b(x.x), f2b(x.y), f2b(x.z), f2b(x.w)};
        *reinterpret_cast<ushort4*>(&lB[sr * LDT + sc + i * 4]) = hh;
      }
    }
    __syncthreads();
    bf16x8 aF[4], bF[4];
    #pragma unroll
    for (int ai = 0; ai < 4; ai++)
      aF[ai] = *reinterpret_cast<const bf16x8*>(&lA[(wr * 64 + ai * 16 + lr) * LDT + lg * 8]);
    #pragma unroll
    for (int bj = 0; bj < 4; bj++)
      bF[bj] = *reinterpret_cast<const bf16x8*>(&lB[(wc * 64 + bj * 16 + lr) * LDT + lg * 8]);
    #pragma unroll
    for (int ai = 0; ai < 4; ai++)
      #pragma unroll
      for (int bj = 0; bj < 4; bj++)
        acc[ai][bj] = __builtin_amdgcn_mfma_f32_16x16x32_bf16(aF[ai], bF[bj], acc[ai][bj], 0, 0, 0);
  }
  #pragma unroll
  for (int ai = 0; ai < 4; ai++) {
    #pragma unroll
    for (int bj = 0; bj < 4; bj++) {
      #pragma unroll
      for (int j = 0; j < 4; j++) {
        int m = mt + wr * 64 + ai * 16 + lg * 4 + j;
        int c = nt + wc * 64 + bj * 16 + lr;
        out[(size_t)m * 512 + c] = acc[ai][bj][j] + bias[c] + resid[(size_t)m * 512 + c];
      }
    }
  }
}

// ---------------- fused attention (R7 structure, coalesced ag stores) ------
// grid (16, H=8, B=8), 256 threads = 4 waves; wave owns 16 q rows, full k.
__global__ __launch_bounds__(256) void attn_kernel(
    const unsigned short* __restrict__ qen,  // [8192,512] bf16 (pre-scaled 1/8)
    const unsigned short* __restrict__ qex,  // [8192,512] bf16 (pre-scaled 1/8)
    const unsigned short* __restrict__ kh,   // [8192,512] bf16
    const unsigned short* __restrict__ vhT,  // [B,H,64,1024] bf16
    const int* __restrict__ etype,           // [B,1024]
    const unsigned int* __restrict__ mbits,  // [B*1024][32] bit-packed mask
    float* __restrict__ attn_g,              // [B,H,1024,1024] f32
    unsigned short* __restrict__ pv_out) {   // [8192,512] bf16
  int qt = blockIdx.x, h = blockIdx.y, b = blockIdx.z;
  int t = threadIdx.x, w = t >> 6, l = t & 63, lr = l & 15, lg = l >> 4;
  __shared__ unsigned int ekbits[32];                 // event bit per k
  __shared__ unsigned int mkill[64 * 33];             // mask & evq, per q-row
  __shared__ __align__(16) unsigned short klds[2][2048]; // dbuf, 32r x 64c swz
  __shared__ __align__(16) unsigned short vlds[2][2048]; // dbuf, 64r x 32c swz
  __shared__ __align__(16) unsigned short pbuf[4][16][40];

  // Q fragments (pre-barrier, global only)
  int qb = qt * 64 + w * 16;
  int qrowA = qb + lr;
  bool evA = etype[b * 1024 + qrowA] != 0;
  const unsigned short* qp = evA ? qen : qex;
  size_t qoff = (size_t)(b * 1024 + qrowA) * 512 + h * 64;
  bf16x8 a0 = *reinterpret_cast<const bf16x8*>(qp + qoff + lg * 8);
  bf16x8 a1 = *reinterpret_cast<const bf16x8*>(qp + qoff + 32 + lg * 8);

  // event bits for k range (32 words x 32 bits)
  if (t < 32) {
    unsigned int wdd = 0;
    const int4* ep = (const int4*)(etype + b * 1024 + t * 32);
    #pragma unroll
    for (int j4 = 0; j4 < 8; j4++) {
      int4 e = ep[j4];
      wdd |= ((e.x != 0 ? 1u : 0u) << (j4 * 4)) | ((e.y != 0 ? 1u : 0u) << (j4 * 4 + 1)) |
             ((e.z != 0 ? 1u : 0u) << (j4 * 4 + 2)) | ((e.w != 0 ? 1u : 0u) << (j4 * 4 + 3));
    }
    ekbits[t] = wdd;
  }
  // kill words: mask bit AND q-row-is-en
  {
    const unsigned int* mslice = mbits + ((size_t)(b * 1024 + qt * 64)) * 32;
    for (int i = t; i < 2048; i += 256) {
      int row = i >> 5, wd = i & 31;
      bool evq_row = etype[b * 1024 + qt * 64 + row] != 0;
      mkill[row * 33 + wd] = evq_row ? mslice[i] : 0u;
    }
  }

  int qrc[4], qlc[4];
  #pragma unroll
  for (int j = 0; j < 4; j++) { qlc[j] = w * 16 + lg * 4 + j; qrc[j] = qt * 64 + qlc[j]; }

  // staging coords (gload_lds: per-wave base, HW adds lane*16)
  int srow = t >> 3, sb8 = t & 7;
  const unsigned short* kgsrc = kh + ((size_t)(b * 1024) + srow) * 512 + h * 64
                                + ((sb8 ^ (srow & 7)) << 3);
  unsigned short* kdst0 = &klds[0][(t & 192) * 8];
  unsigned short* kdst1 = &klds[1][(t & 192) * 8];
  int vrow = t >> 2, vb4 = t & 3;
  const unsigned short* vb_base = vhT + ((size_t)((b * 8 + h) * 64)) * 1024;
  const unsigned short* vgsrc = vb_base + (size_t)vrow * 1024 + ((vb4 ^ ((vrow >> 1) & 3)) << 3);
  unsigned short* vdst0 = &vlds[0][(t & 192) * 8];
  unsigned short* vdst1 = &vlds[1][(t & 192) * 8];

  // ================= PASS 1: denominators =================
  gload16(kgsrc, kdst0);
  __syncthreads();   // stage(chunk0) done + ekbits/mkill visible

  float srun[4] = {0.f, 0.f, 0.f, 0.f};
  for (int c = 0; c < 32; c++) {
    int cur = c & 1;
    if (c < 31) gload16(kgsrc + (size_t)(c + 1) * 32 * 512, cur ? kdst0 : kdst1);
    #pragma unroll
    for (int c2 = 0; c2 < 2; c2++) {
      int kt = c * 2 + c2;
      int row = c2 * 16 + lr, r7 = row & 7;
      bf16x8 b0 = *reinterpret_cast<const bf16x8*>(&klds[cur][row * 64 + ((lg ^ r7) << 3)]);
      bf16x8 b1 = *reinterpret_cast<const bf16x8*>(&klds[cur][row * 64 + (((4 + lg) ^ r7) << 3)]);
      f32x4 cc = {0.f, 0.f, 0.f, 0.f};
      cc = __builtin_amdgcn_mfma_f32_16x16x32_bf16(a0, b0, cc, 0, 0, 0);
      cc = __builtin_amdgcn_mfma_f32_16x16x32_bf16(a1, b1, cc, 0, 0, 0);
      int wcol = kt >> 1, bitpos = ((kt & 1) << 4) + lr;
      bool ekb = (ekbits[wcol] >> bitpos) & 1;
      #pragma unroll
      for (int j = 0; j < 4; j++) {
        bool mk = (mkill[qlc[j] * 33 + wcol] >> bitpos) & 1;
        float val = ekb ? (mk ? NEGV : cc[j]) : 0.f;
        srun[j] += __expf(val);
      }
    }
    __syncthreads();
  }
  float rS[4];
  #pragma unroll
  for (int j = 0; j < 4; j++) {
    float s = srun[j];
    s += __shfl_xor(s, 1); s += __shfl_xor(s, 2);
    s += __shfl_xor(s, 4); s += __shfl_xor(s, 8);
    rS[j] = 1.f / s;
  }

  // ================= PASS 2: attn write + PV =================
  f32x4 oacc[4];
  #pragma unroll
  for (int n = 0; n < 4; n++) oacc[n] = {0.f, 0.f, 0.f, 0.f};
  float* ag = attn_g + ((size_t)(b * 8 + h)) * 1024 * 1024;
  float* agrow = ag + (size_t)(qb + lr) * 1024 + lg * 8;

  gload16(kgsrc, kdst0);
  gload16(vgsrc, vdst0);
  __syncthreads();

  for (int c = 0; c < 32; c++) {
    int cur = c & 1;
    if (c < 31) {
      gload16(kgsrc + (size_t)(c + 1) * 32 * 512, cur ? kdst0 : kdst1);
      gload16(vgsrc + (size_t)(c + 1) * 32, cur ? vdst0 : vdst1);
    }
    #pragma unroll
    for (int c2 = 0; c2 < 2; c2++) {
      int kt = c * 2 + c2;
      int row = c2 * 16 + lr, r7 = row & 7;
      bf16x8 b0 = *reinterpret_cast<const bf16x8*>(&klds[cur][row * 64 + ((lg ^ r7) << 3)]);
      bf16x8 b1 = *reinterpret_cast<const bf16x8*>(&klds[cur][row * 64 + (((4 + lg) ^ r7) << 3)]);
      f32x4 cc = {0.f, 0.f, 0.f, 0.f};
      cc = __builtin_amdgcn_mfma_f32_16x16x32_bf16(a0, b0, cc, 0, 0, 0);
      cc = __builtin_amdgcn_mfma_f32_16x16x32_bf16(a1, b1, cc, 0, 0, 0);
      int wcol = kt >> 1, bitpos = ((kt & 1) << 4) + lr;
      bool ekb = (ekbits[wcol] >> bitpos) & 1;
      #pragma unroll
      for (int j = 0; j < 4; j++) {
        bool mk = (mkill[qlc[j] * 33 + wcol] >> bitpos) & 1;
        float val = ekb ? (mk ? NEGV : cc[j]) : 0.f;
        float p = __expf(val) * rS[j];
        pbuf[w][lg * 4 + j][(c2 << 4) + lr] = f2b(p);
      }
      if (c2) {
        bf16x8 pa = *reinterpret_cast<const bf16x8*>(&pbuf[w][lr][lg * 8]);
        // coalesced attn store: row qb+lr, cols c*32 + lg*8 .. +8
        f32x4 f0, f1;
        f0[0] = sb2f(pa[0]); f0[1] = sb2f(pa[1]); f0[2] = sb2f(pa[2]); f0[3] = sb2f(pa[3]);
        f1[0] = sb2f(pa[4]); f1[1] = sb2f(pa[5]); f1[2] = sb2f(pa[6]); f1[3] = sb2f(pa[7]);
        __builtin_nontemporal_store(f0, reinterpret_cast<f32x4*>(agrow + c * 32));
        __builtin_nontemporal_store(f1, reinterpret_cast<f32x4*>(agrow + c * 32 + 4));
        #pragma unroll
        for (int n = 0; n < 4; n++) {
          int vr = n * 16 + lr;
          int cb = (lg ^ ((vr >> 1) & 3)) << 3;
          bf16x8 vb = *reinterpret_cast<const bf16x8*>(&vlds[cur][vr * 32 + cb]);
          oacc[n] = __builtin_amdgcn_mfma_f32_16x16x32_bf16(pa, vb, oacc[n], 0, 0, 0);
        }
      }
    }
    __syncthreads();
  }
  #pragma unroll
  for (int n = 0; n < 4; n++) {
    #pragma unroll
    for (int j = 0; j < 4; j++) {
      __builtin_nontemporal_store(f2b(oacc[n][j]),
          &pv_out[(size_t)(b * 1024 + qrc[j]) * 512 + h * 64 + n * 16 + lr]);
    }
  }
}

extern "C" void kernel_launch(void* const* d_in, const int* in_sizes, int n_in,
                              void* d_out, int out_size, void* d_ws, size_t ws_size,
                              hipStream_t stream) {
  (void)in_sizes; (void)n_in; (void)out_size; (void)ws_size;
  const float* q     = (const float*)d_in[0];
  const float* k     = (const float*)d_in[1];
  const float* v     = (const float*)d_in[2];
  const int* etype   = (const int*)d_in[3];
  const void* mask_raw = d_in[4];
  const float* w_qs  = (const float*)d_in[5];
  const float* w_ex  = (const float*)d_in[6];
  const float* w_ks  = (const float*)d_in[7];
  const float* w_vs  = (const float*)d_in[8];
  const float* w_fc  = (const float*)d_in[9];
  const float* b_fc  = (const float*)d_in[10];
  const float* gamma = (const float*)d_in[11];
  const float* beta  = (const float*)d_in[12];

  char* ws = (char*)d_ws;
  const size_t MB = 1024 * 1024;
  unsigned short* qn   = (unsigned short*)(ws);            // 8 MB bf16
  unsigned short* qen  = (unsigned short*)(ws + 8 * MB);
  unsigned short* qex  = (unsigned short*)(ws + 16 * MB);
  unsigned short* khb  = (unsigned short*)(ws + 24 * MB);
  unsigned short* vhT  = (unsigned short*)(ws + 32 * MB);
  unsigned short* ao   = (unsigned short*)(ws + 40 * MB);
  unsigned int* mbits  = (unsigned int*)(ws + 48 * MB);    // 1 MB
  int* mflag           = (int*)(ws + 49 * MB);

  float* outp = (float*)d_out;
  float* attn_g = outp + (size_t)8 * 1024 * 512;

  ln_kernel<<<8192, 256, 0, stream>>>(q, gamma, beta, qn);

  const int MASK_N = 8 * 1024 * 1024;
  hipMemsetAsync(mflag, 0, 4, stream);
  mask_detect<<<2048, 256, 0, stream>>>((const unsigned int*)mask_raw, MASK_N / 4, mflag);
  const int NWORDS = MASK_N / 32;
  mask_canon_bits<<<(NWORDS + 255) / 256, 256, 0, stream>>>(mask_raw, mbits, NWORDS, mflag);

  proj_gemm<<<dim3(64, 4, 4), 256, 0, stream>>>(qn, k, v, w_qs, w_ex, w_ks, w_vs,
                                                qen, qex, khb, vhT);

  attn_kernel<<<dim3(16, 8, 8), 256, 0, stream>>>(qen, qex, khb, vhT, etype, mbits,
                                                  attn_g, ao);

  fc_gemm<<<dim3(64, 4), 256, 0, stream>>>(ao, w_fc, b_fc, q, outp);
}